// Round 6
// baseline (349.233 us; speedup 1.0000x reference)
//
#include <hip/hip_runtime.h>
#include <cmath>

typedef __attribute__((ext_vector_type(8))) short short8;
typedef __attribute__((ext_vector_type(4))) float f32x4;
typedef __attribute__((ext_vector_type(4))) unsigned short us4;
typedef unsigned short u16;

#define BATCH 8192
#define HDIM  256
static constexpr size_t BH = (size_t)BATCH * HDIM;  // 2,097,152

__device__ __forceinline__ u16 f2bf(float f) {
    union { float f; unsigned u; } v; v.f = f;
    unsigned r = v.u + 0x7FFFu + ((v.u >> 16) & 1u);
    return (u16)(r >> 16);
}
__device__ __forceinline__ float bf2f(u16 u) {
    union { unsigned u; float f; } v; v.u = ((unsigned)u) << 16;
    return v.f;
}
__device__ __forceinline__ float wred(float v) {
#pragma unroll
    for (int o = 32; o > 0; o >>= 1) v += __shfl_xor(v, o);
    return v;
}
__device__ __forceinline__ float sigmoidf_(float x) {
    return 1.f / (1.f + __expf(-x));
}
__device__ __forceinline__ short8 cvt8(const float* p) {
    f32x4 lo = *(const f32x4*)p, hi = *(const f32x4*)(p + 4);
    short8 t;
    t[0] = (short)f2bf(lo[0]); t[1] = (short)f2bf(lo[1]);
    t[2] = (short)f2bf(lo[2]); t[3] = (short)f2bf(lo[3]);
    t[4] = (short)f2bf(hi[0]); t[5] = (short)f2bf(hi[1]);
    t[6] = (short)f2bf(hi[2]); t[7] = (short)f2bf(hi[3]);
    return t;
}

// ---------------- weight conversion: pack all needed weights to bf16 ----------------
// dst layout (u16 units, 65536 per chunk):
//  c0: embed_w | c1..4: wtn[l] | c5..8: wsn[l] | c9..12: wt[l][512:768]
//  c13..16: ws[l][0:256] | c17..20: ws[l][512:768] | c21: out_w
__global__ __launch_bounds__(256) void convert_weights(
    const float* __restrict__ embed_w, const float* __restrict__ wtn,
    const float* __restrict__ wsn, const float* __restrict__ wt,
    const float* __restrict__ ws, const float* __restrict__ out_w,
    u16* __restrict__ dst)
{
    int idx = blockIdx.x * 256 + threadIdx.x;
    int e = idx * 4;
    if (e >= 22 * 65536) return;
    int c = e >> 16, o = e & 65535;
    const float* src;
    if (c == 0)      src = embed_w + o;
    else if (c < 5)  src = wtn + (size_t)(c - 1) * 65536 + o;
    else if (c < 9)  src = wsn + (size_t)(c - 5) * 65536 + o;
    else if (c < 13) src = wt + (size_t)(c - 9) * 768 * 256 + 512 * 256 + o;
    else if (c < 17) src = ws + (size_t)(c - 13) * 768 * 256 + o;
    else if (c < 21) src = ws + (size_t)(c - 17) * 768 * 256 + 512 * 256 + o;
    else             src = out_w + o;
    f32x4 v = *(const f32x4*)src;
    us4 r;
#pragma unroll
    for (int j = 0; j < 4; ++j) r[j] = f2bf(v[j]);
    *(us4*)(dst + e) = r;
}

#define PAD 264  // u16 LDS row stride

// ---------------- embed: S0 = x @ embed_w^T + b (full occupancy col-split) ----------------
// grid (512, 4), 256 thr (4 waves). Block: 16 rows x 64 cols; wave w: 16 cols.
__global__ __launch_bounds__(256, 8) void gemm_embed(
    const float* __restrict__ x, const u16* __restrict__ W,
    const float* __restrict__ bias, u16* __restrict__ S0)
{
    __shared__ __align__(16) u16 A[16][PAD];
    const int t = threadIdx.x;
    const int row0 = blockIdx.x * 16;
    {   // stage x tile -> bf16 LDS
        int r = t >> 4, c = (t & 15) * 16;
        const float* p = x + (size_t)(row0 + r) * 256 + c;
        *(short8*)&A[r][c] = cvt8(p);
        *(short8*)&A[r][c + 8] = cvt8(p + 8);
    }
    __syncthreads();
    const int lane = t & 63, wave = t >> 6;
    const int lr = lane & 15, kg = lane >> 4;
    const int n = blockIdx.y * 64 + wave * 16 + lr;
    f32x4 acc = {};
    for (int k0 = 0; k0 < 256; k0 += 32) {
        int k = k0 + kg * 8;
        short8 a = *(const short8*)&A[lr][k];
        short8 b = *(const short8*)(W + (size_t)n * 256 + k);
        acc = __builtin_amdgcn_mfma_f32_16x16x32_bf16(a, b, acc, 0, 0, 0);
    }
    float bn = bias[n];
#pragma unroll
    for (int r = 0; r < 4; ++r)
        S0[(size_t)(row0 + kg * 4 + r) * 256 + n] = f2bf(acc[r] + bn);
}

// ---------------- out = tanh(S4 @ out_w^T + b), f32 ----------------
__global__ __launch_bounds__(256, 8) void gemm_out(
    const u16* __restrict__ S4, const u16* __restrict__ W,
    const float* __restrict__ bias, float* __restrict__ outp)
{
    __shared__ __align__(16) u16 A[16][PAD];
    const int t = threadIdx.x;
    const int row0 = blockIdx.x * 16;
    {
        int r = t >> 4, c = (t & 15) * 16;
        const u16* p = S4 + (size_t)(row0 + r) * 256 + c;
        *(short8*)&A[r][c] = *(const short8*)p;
        *(short8*)&A[r][c + 8] = *(const short8*)(p + 8);
    }
    __syncthreads();
    const int lane = t & 63, wave = t >> 6;
    const int lr = lane & 15, kg = lane >> 4;
    const int n = blockIdx.y * 64 + wave * 16 + lr;
    f32x4 acc = {};
    for (int k0 = 0; k0 < 256; k0 += 32) {
        int k = k0 + kg * 8;
        short8 a = *(const short8*)&A[lr][k];
        short8 b = *(const short8*)(W + (size_t)n * 256 + k);
        acc = __builtin_amdgcn_mfma_f32_16x16x32_bf16(a, b, acc, 0, 0, 0);
    }
    float bn = bias[n];
#pragma unroll
    for (int r = 0; r < 4; ++r)
        outp[(size_t)(row0 + kg * 4 + r) * 256 + n] = tanhf(acc[r] + bn);
}

// ---------------- triple GEMM + gated combine (full occupancy col-split) ----------------
// Sout = sig(Sf@Ws1^T+b2) * (Sf@Ws3^T+b3) + (1-sig)*(Tf@Wt3^T+b1)
__global__ __launch_bounds__(256, 8) void gemm_triple(
    const u16* __restrict__ Tf, const u16* __restrict__ Sf,
    const u16* __restrict__ Wt3, const u16* __restrict__ Ws1, const u16* __restrict__ Ws3,
    const float* __restrict__ b1p, const float* __restrict__ b2p, const float* __restrict__ b3p,
    u16* __restrict__ Sout)
{
    __shared__ __align__(16) u16 At[16][PAD];
    __shared__ __align__(16) u16 As[16][PAD];
    const int t = threadIdx.x;
    const int row0 = blockIdx.x * 16;
    {
        int r = t >> 4, c = (t & 15) * 16;
        size_t off = (size_t)(row0 + r) * 256 + c;
        *(short8*)&At[r][c]     = *(const short8*)(Tf + off);
        *(short8*)&At[r][c + 8] = *(const short8*)(Tf + off + 8);
        *(short8*)&As[r][c]     = *(const short8*)(Sf + off);
        *(short8*)&As[r][c + 8] = *(const short8*)(Sf + off + 8);
    }
    __syncthreads();
    const int lane = t & 63, wave = t >> 6;
    const int lr = lane & 15, kg = lane >> 4;
    const int n = blockIdx.y * 64 + wave * 16 + lr;
    f32x4 aT = {}, aG = {}, aS = {};
    for (int k0 = 0; k0 < 256; k0 += 32) {
        int k = k0 + kg * 8;
        short8 at = *(const short8*)&At[lr][k];
        short8 as = *(const short8*)&As[lr][k];
        size_t wo = (size_t)n * 256 + k;
        aT = __builtin_amdgcn_mfma_f32_16x16x32_bf16(at, *(const short8*)(Wt3 + wo), aT, 0, 0, 0);
        aG = __builtin_amdgcn_mfma_f32_16x16x32_bf16(as, *(const short8*)(Ws1 + wo), aG, 0, 0, 0);
        aS = __builtin_amdgcn_mfma_f32_16x16x32_bf16(as, *(const short8*)(Ws3 + wo), aS, 0, 0, 0);
    }
    float bb1 = b1p[n], bb2 = b2p[n], bb3 = b3p[n];
#pragma unroll
    for (int r = 0; r < 4; ++r) {
        float gv = sigmoidf_(aG[r] + bb2);
        float v = gv * (aS[r] + bb3) + (1.f - gv) * (aT[r] + bb1);
        Sout[(size_t)(row0 + kg * 4 + r) * 256 + n] = f2bf(v);
    }
}

// ---------------- attn_dual: dual GEMM (LDS) + attention, deep load batching ----------------
// grid 512, 256 thr (4 waves), launch_bounds(256,2) -> up to 256 VGPR, 8 waves/CU.
// Phase A: wave w computes s_next/t_next cols [64w,64w+64) for 16 rows -> LDS.
// Phase B: wave w handles rows 4w..4w+3 in 2-row batches (~38 loads in flight).
__global__ __launch_bounds__(256, 2) void attn_dual(
    const float* __restrict__ t_att, const float* __restrict__ s_att,
    const u16* __restrict__ S_hist, const u16* __restrict__ Wbf,
    const float* __restrict__ btn, const float* __restrict__ bsn,
    u16* __restrict__ tf_g, u16* __restrict__ sf_g, int layer)
{
    __shared__ __align__(16) u16 sn_lds[16][PAD];
    __shared__ __align__(16) u16 tn_lds[16][PAD];

    const int lane = threadIdx.x & 63;
    const int wave = threadIdx.x >> 6;  // 0..3
    const int lr = lane & 15;
    const int kg = lane >> 4;
    const int row0 = blockIdx.x * 16;
    const float scale = 0.0625f;

    // ---- Phase A: dual GEMM ----
    {
        const int n0 = wave * 64;
        const u16* Wsn = Wbf + (size_t)(5 + layer) * 65536;
        const u16* Wtn = Wbf + (size_t)(1 + layer) * 65536;
        const u16* Scur = S_hist + (size_t)layer * BH;
        const float* Tlast = t_att + ((size_t)layer * 8 + 7) * BH;
        f32x4 accS[4] = {}, accT[4] = {};
        for (int k0 = 0; k0 < 256; k0 += 32) {
            int k = k0 + kg * 8;
            short8 aS = *(const short8*)(Scur + (size_t)(row0 + lr) * 256 + k);
            short8 aT = cvt8(Tlast + (size_t)(row0 + lr) * 256 + k);
#pragma unroll
            for (int nf = 0; nf < 4; ++nf) {
                size_t wo = (size_t)(n0 + nf * 16 + lr) * 256 + k;
                accS[nf] = __builtin_amdgcn_mfma_f32_16x16x32_bf16(aS, *(const short8*)(Wsn + wo), accS[nf], 0, 0, 0);
                accT[nf] = __builtin_amdgcn_mfma_f32_16x16x32_bf16(aT, *(const short8*)(Wtn + wo), accT[nf], 0, 0, 0);
            }
        }
#pragma unroll
        for (int nf = 0; nf < 4; ++nf) {
            int n = n0 + nf * 16 + lr;
            float bS = bsn[layer * 256 + n];
            float bT = btn[layer * 256 + n];
#pragma unroll
            for (int r = 0; r < 4; ++r) {
                sn_lds[kg * 4 + r][n] = f2bf(accS[nf][r] + bS);
                tn_lds[kg * 4 + r][n] = f2bf(accT[nf][r] + bT);
            }
        }
    }
    __syncthreads();

    // ---- Phase B: attention, 2-row batches ----
    for (int rp = 0; rp < 4; rp += 2) {
        f32x4 sav[2][7], tav[2][8], tspv[2][3];
        us4 shu[2][3], scu[2], snu[2], tnu[2];
#pragma unroll
        for (int q = 0; q < 2; ++q) {
            const int rr = wave * 4 + rp + q;
            const size_t ro = (size_t)(row0 + rr) * 256 + lane * 4;
            const float* sa = s_att + (size_t)layer * 8 * BH + ro;
            const float* ta = t_att + (size_t)layer * 8 * BH + ro;
#pragma unroll
            for (int kk = 0; kk < 7; ++kk) sav[q][kk] = *(const f32x4*)(sa + (size_t)(kk + 1) * BH);
#pragma unroll
            for (int kk = 0; kk < 8; ++kk) tav[q][kk] = *(const f32x4*)(ta + (size_t)kk * BH);
#pragma unroll
            for (int jj = 0; jj < 3; ++jj)
                if (jj < layer) {
                    tspv[q][jj] = *(const f32x4*)(t_att + ((size_t)jj * 8 + 7) * BH + ro);
                    shu[q][jj]  = *(const us4*)(S_hist + (size_t)jj * BH + ro);
                }
            scu[q] = *(const us4*)(S_hist + (size_t)layer * BH + ro);
            snu[q] = *(const us4*)&sn_lds[rr][lane * 4];
            tnu[q] = *(const us4*)&tn_lds[rr][lane * 4];
        }
#pragma unroll
        for (int q = 0; q < 2; ++q) {
            const int rr = wave * 4 + rp + q;
            const size_t ro = (size_t)(row0 + rr) * 256 + lane * 4;
            float sn[4], tn[4], Sc[4];
#pragma unroll
            for (int j = 0; j < 4; ++j) { sn[j] = bf2f(snu[q][j]); tn[j] = bf2f(tnu[q][j]); Sc[j] = bf2f(scu[q][j]); }

            // temporal logits: keys = s_att[i,1:] ++ [S]
            float lt[8];
#pragma unroll
            for (int kk = 0; kk < 7; ++kk)
                lt[kk] = wred(sav[q][kk][0] * sn[0] + sav[q][kk][1] * sn[1] + sav[q][kk][2] * sn[2] + sav[q][kk][3] * sn[3]) * scale;
            lt[7] = wred(Sc[0] * sn[0] + Sc[1] * sn[1] + Sc[2] * sn[2] + Sc[3] * sn[3]) * scale;

            float m = lt[0];
#pragma unroll
            for (int kk = 1; kk < 8; ++kk) m = fmaxf(m, lt[kk]);
            float w8[8], den = 0.f;
#pragma unroll
            for (int kk = 0; kk < 8; ++kk) { w8[kk] = __expf(lt[kk] - m); den += w8[kk]; }
            float inv = 1.f / den;

            float Tt[4] = {0.f, 0.f, 0.f, 0.f};
#pragma unroll
            for (int kk = 0; kk < 8; ++kk)
#pragma unroll
                for (int j = 0; j < 4; ++j) Tt[j] += w8[kk] * tav[q][kk][j];
            us4 ot;
#pragma unroll
            for (int j = 0; j < 4; ++j) {
                float g = sigmoidf_(tn[j]);
                ot[j] = f2bf(tav[q][7][j] * g + (1.f - g) * Tt[j] * inv);
            }
            *(us4*)(tf_g + ro) = ot;

            // spatial: keys = [zeros x (7-layer), t_att[0,7]..t_att[layer,7]]
            float lsp[4];
#pragma unroll
            for (int jj = 0; jj < 3; ++jj)
                if (jj < layer)
                    lsp[jj] = wred(tspv[q][jj][0] * tn[0] + tspv[q][jj][1] * tn[1] + tspv[q][jj][2] * tn[2] + tspv[q][jj][3] * tn[3]) * scale;
            lsp[3] = wred(tav[q][7][0] * tn[0] + tav[q][7][1] * tn[1] + tav[q][7][2] * tn[2] + tav[q][7][3] * tn[3]) * scale;

            float ms = fmaxf(0.f, lsp[3]);
#pragma unroll
            for (int jj = 0; jj < 3; ++jj)
                if (jj < layer) ms = fmaxf(ms, lsp[jj]);
            float dens = (float)(7 - layer) * __expf(-ms);
            float St[4] = {0.f, 0.f, 0.f, 0.f};
#pragma unroll
            for (int jj = 0; jj < 3; ++jj)
                if (jj < layer) {
                    float w = __expf(lsp[jj] - ms);
                    dens += w;
#pragma unroll
                    for (int j = 0; j < 4; ++j) St[j] += w * bf2f(shu[q][jj][j]);
                }
            {
                float w = __expf(lsp[3] - ms);
                dens += w;
#pragma unroll
                for (int j = 0; j < 4; ++j) St[j] += w * Sc[j];
            }
            float invs = 1.f / dens;
            us4 os;
#pragma unroll
            for (int j = 0; j < 4; ++j) {
                float g = sigmoidf_(sn[j]);
                os[j] = f2bf(Sc[j] * g + (1.f - g) * St[j] * invs);
            }
            *(us4*)(sf_g + ro) = os;
        }
    }
}

extern "C" void kernel_launch(void* const* d_in, const int* in_sizes, int n_in,
                              void* d_out, int out_size, void* d_ws, size_t ws_size,
                              hipStream_t stream)
{
    (void)in_sizes; (void)n_in; (void)out_size; (void)ws_size;
    const float* x       = (const float*)d_in[0];
    const float* t_att   = (const float*)d_in[1];
    const float* s_att   = (const float*)d_in[2];
    const float* embed_w = (const float*)d_in[3];
    const float* embed_b = (const float*)d_in[4];
    const float* wtn     = (const float*)d_in[5];
    const float* btn     = (const float*)d_in[6];
    const float* wsn     = (const float*)d_in[7];
    const float* bsn     = (const float*)d_in[8];
    const float* wt      = (const float*)d_in[9];
    const float* bt      = (const float*)d_in[10];
    const float* ws_in   = (const float*)d_in[11];
    const float* bs      = (const float*)d_in[12];
    const float* out_w   = (const float*)d_in[13];
    const float* out_b   = (const float*)d_in[14];

    u16* wsp    = (u16*)d_ws;
    u16* Wbf    = wsp;                       // 22 * 65536 u16
    u16* S_hist = wsp + (size_t)22 * 65536;  // 5 * BH
    u16* tf_g   = S_hist + 5 * BH;           // BH
    u16* sf_g   = tf_g + BH;                 // BH

    convert_weights<<<1408, 256, 0, stream>>>(embed_w, wtn, wsn, wt, ws_in, out_w, Wbf);

    dim3 gg(BATCH / 16, 4);

    gemm_embed<<<gg, 256, 0, stream>>>(x, Wbf, embed_b, S_hist);

    for (int i = 0; i < 4; ++i) {
        attn_dual<<<BATCH / 16, 256, 0, stream>>>(t_att, s_att, S_hist, Wbf,
                                                  btn, bsn, tf_g, sf_g, i);
        gemm_triple<<<gg, 256, 0, stream>>>(tf_g, sf_g,
                                            Wbf + (size_t)(9 + i) * 65536,
                                            Wbf + (size_t)(13 + i) * 65536,
                                            Wbf + (size_t)(17 + i) * 65536,
                                            bt + i * 768 + 512, bs + i * 768, bs + i * 768 + 512,
                                            S_hist + (size_t)(i + 1) * BH);
    }

    gemm_out<<<gg, 256, 0, stream>>>(S_hist + (size_t)4 * BH,
                                     Wbf + (size_t)21 * 65536, out_b, (float*)d_out);
}